// Round 1
// baseline (356.922 us; speedup 1.0000x reference)
//
#include <hip/hip_runtime.h>
#include <hip/hip_bf16.h>

// DomainEncoder: 8-expert MoE MLP, N=32768, 256 -> 1024 (LN+ReLU) -> 256.
// Pipeline:
//   1. transpose W1,W2 -> bf16 [N,K] ("B^T" layout for the m97 GEMM structure)
//   2. counting-sort rows by domain into 128-aligned segments (perm + gather x->bf16)
//   3. GEMM-A: h = x_s @ W1[d]^T + b1   (bf16 MFMA 16x16x32, 128x128 tiles)
//   4. LN + ReLU over h rows (1024 wide), in place, bf16
//   5. GEMM-B: out = g @ W2[d]^T + b2, scattered back through perm (fp32 out)

#define ND 8
#define NROWS 32768
#define DIN 256
#define DHID 1024
#define DOUT 256
#define MPAD 33792          // 32768 + 8*128 worst-case padding
#define NTILES 264          // 256 + 8 worst-case row tiles

typedef short short8 __attribute__((ext_vector_type(8)));
typedef float floatx4 __attribute__((ext_vector_type(4)));

__device__ __forceinline__ unsigned short f2bf(float f) {
    unsigned u = __builtin_bit_cast(unsigned, f);
    unsigned r = u + 0x7fff + ((u >> 16) & 1);   // RNE (inputs finite)
    return (unsigned short)(r >> 16);
}
__device__ __forceinline__ float bf2f(unsigned short h) {
    unsigned u = ((unsigned)h) << 16;
    return __builtin_bit_cast(float, u);
}

#define GLDS16(gp, lp) __builtin_amdgcn_global_load_lds( \
    (const __attribute__((address_space(1))) void*)(gp), \
    (__attribute__((address_space(3))) void*)(lp), 16, 0, 0)

// ---------------- 1. weight transpose fp32[R,C] -> bf16[C,R], per-domain z ----
__global__ void transpose_bf16(const float* __restrict__ in,
                               unsigned short* __restrict__ out,
                               int R, int C) {
    __shared__ float t[32][33];
    const int z = blockIdx.z;
    const int c0 = blockIdx.x * 32, r0 = blockIdx.y * 32;
    const int tx = threadIdx.x & 31, ty = threadIdx.x >> 5;   // 32x8
    const float* src = in + (size_t)z * R * C;
    unsigned short* dst = out + (size_t)z * R * C;
#pragma unroll
    for (int i = 0; i < 32; i += 8)
        t[ty + i][tx] = src[(size_t)(r0 + ty + i) * C + c0 + tx];
    __syncthreads();
#pragma unroll
    for (int i = 0; i < 32; i += 8)
        dst[(size_t)(c0 + ty + i) * R + r0 + tx] = f2bf(t[tx][ty + i]);
}

// ---------------- 2a. init perm/rowdom/counters -------------------------------
__global__ void zero_init(int* __restrict__ perm, int* __restrict__ rowdom,
                          int* __restrict__ cnt) {
    int i = blockIdx.x * 256 + threadIdx.x;
    if (i < MPAD) { perm[i] = -1; rowdom[i] = 0; }
    if (i < 16) cnt[i] = 0;            // counts[8] + cursors[8]
}

// ---------------- 2b. histogram ----------------------------------------------
__global__ void histo(const int* __restrict__ dt, int* __restrict__ counts) {
    __shared__ int lc[ND];
    if (threadIdx.x < ND) lc[threadIdx.x] = 0;
    __syncthreads();
    int i = blockIdx.x * 256 + threadIdx.x;      // grid covers exactly NROWS
    atomicAdd(&lc[dt[i]], 1);
    __syncthreads();
    if (threadIdx.x < ND) atomicAdd(&counts[threadIdx.x], lc[threadIdx.x]);
}

// ---------------- 2c. aligned offsets + tile metadata (single thread) ---------
__global__ void make_meta(const int* __restrict__ counts, int* __restrict__ cursors,
                          int2* __restrict__ meta) {
    if (threadIdx.x == 0 && blockIdx.x == 0) {
        int off = 0, t = 0;
        for (int d = 0; d < ND; d++) {
            cursors[d] = off;
            int nt = (counts[d] + 127) >> 7;
            for (int i = 0; i < nt; i++) meta[t++] = make_int2(d, off + (i << 7));
            off += nt << 7;
        }
        for (; t < NTILES; t++) meta[t] = make_int2(-1, 0);
    }
}

// ---------------- 2d. gather x rows into sorted bf16 buffer -------------------
__global__ void gather_rows(const float* __restrict__ x, const int* __restrict__ dt,
                            int* __restrict__ cursors, int* __restrict__ perm,
                            int* __restrict__ rowdom, unsigned short* __restrict__ xs) {
    __shared__ int s_pos[64];
    const int tid = threadIdx.x;
    const int r = blockIdx.x * 64 + (tid >> 2);
    if ((tid & 3) == 0) {
        int d = dt[r];
        int p = atomicAdd(&cursors[d], 1);
        s_pos[tid >> 2] = p;
        perm[p] = r;
        rowdom[p] = d;
    }
    __syncthreads();
    const int p = s_pos[tid >> 2];
    const float4* src = (const float4*)(x + (size_t)r * DIN);
    unsigned short* dst = xs + (size_t)p * DIN + (tid & 3) * 64;
#pragma unroll
    for (int i = 0; i < 16; i++) {
        float4 v = src[(tid & 3) * 16 + i];
        dst[i * 4 + 0] = f2bf(v.x);
        dst[i * 4 + 1] = f2bf(v.y);
        dst[i * 4 + 2] = f2bf(v.z);
        dst[i * 4 + 3] = f2bf(v.w);
    }
}

// ---------------- 3/5. grouped GEMM, m97 structure ---------------------------
// C[128x128] per block, 4 waves in 2x2, each wave 64x64 = 4x4 mfma_16x16x32_bf16.
// A: [MPAD,K] bf16 row-major (sorted rows). Bt: [ND,Ntot,K] bf16 (B^T).
template <int K, bool SCATTER>
__global__ __launch_bounds__(256, 2)
void gemm_bt(const unsigned short* __restrict__ A,
             const unsigned short* __restrict__ Bt,
             const float* __restrict__ bias,
             const int2* __restrict__ meta,
             const int* __restrict__ perm,
             unsigned short* __restrict__ Cbf,
             float* __restrict__ Cf,
             const int Ntot) {
    const int2 md = meta[blockIdx.x];
    const int dom = md.x;
    if (dom < 0) return;
    const int m0 = md.y;
    const int n0 = blockIdx.y * 128;

    __shared__ unsigned short As[128 * 32];   // [m][k], 8 KB
    __shared__ unsigned short Bs[128 * 32];   // [n][k], 8 KB

    const int tid = threadIdx.x;
    const int lane = tid & 63;
    const int w = tid >> 6;            // wave id 0..3
    const int wr = w >> 1, wc = w & 1; // 2x2 wave grid

    const unsigned short* Abase = A + (size_t)m0 * K;
    const unsigned short* Bbase = Bt + (size_t)dom * Ntot * K + (size_t)n0 * K;

    floatx4 acc[4][4];
#pragma unroll
    for (int i = 0; i < 4; i++)
#pragma unroll
        for (int j = 0; j < 4; j++) acc[i][j] = 0.f;

    for (int k0 = 0; k0 < K; k0 += 32) {
        // stage: chunk c = w*128 + it*64 + lane; 16B chunks, LDS dest = base + lane*16
#pragma unroll
        for (int it = 0; it < 2; ++it) {
            const int c = w * 128 + it * 64 + lane;
            const int m = c >> 2, kc = c & 3;
            GLDS16(Abase + (size_t)m * K + k0 + kc * 8, &As[(w * 128 + it * 64) * 8]);
            GLDS16(Bbase + (size_t)m * K + k0 + kc * 8, &Bs[(w * 128 + it * 64) * 8]);
        }
        __syncthreads();   // drains vmcnt before barrier (global_load_lds complete)

        short8 a[4], b[4];
        const int kk = (lane >> 4) * 8;
#pragma unroll
        for (int i = 0; i < 4; i++) {
            const int m = wr * 64 + i * 16 + (lane & 15);
            a[i] = *(const short8*)&As[m * 32 + kk];
            const int n = wc * 64 + i * 16 + (lane & 15);
            b[i] = *(const short8*)&Bs[n * 32 + kk];
        }
#pragma unroll
        for (int i = 0; i < 4; i++)
#pragma unroll
            for (int j = 0; j < 4; j++)
                acc[i][j] = __builtin_amdgcn_mfma_f32_16x16x32_bf16(a[i], b[j], acc[i][j], 0, 0, 0);
        __syncthreads();
    }

    // epilogue: C/D layout col=lane&15, row=(lane>>4)*4+reg  [m89-verified]
    const int quad = lane >> 4;
#pragma unroll
    for (int i = 0; i < 4; i++) {
        const int rowbase = m0 + wr * 64 + i * 16 + quad * 4;
        if (!SCATTER) {
#pragma unroll
            for (int j = 0; j < 4; j++) {
                const int col = n0 + wc * 64 + j * 16 + (lane & 15);
                const float bv = bias[dom * Ntot + col];
#pragma unroll
                for (int r = 0; r < 4; r++)
                    Cbf[(size_t)(rowbase + r) * Ntot + col] = f2bf(acc[i][j][r] + bv);
            }
        } else {
#pragma unroll
            for (int r = 0; r < 4; r++) {
                const int orig = perm[rowbase + r];
                if (orig < 0) continue;     // padding row
#pragma unroll
                for (int j = 0; j < 4; j++) {
                    const int col = n0 + wc * 64 + j * 16 + (lane & 15);
                    Cf[(size_t)orig * Ntot + col] = acc[i][j][r] + bias[dom * Ntot + col];
                }
            }
        }
    }
}

// ---------------- 4. LayerNorm + ReLU over h rows (1024), in place -----------
__global__ __launch_bounds__(256)
void ln_relu(unsigned short* __restrict__ H, const float* __restrict__ gamma,
             const float* __restrict__ beta, const int* __restrict__ rowdom) {
    const int row = blockIdx.x;
    const int tid = threadIdx.x;
    const int dom = rowdom[row];
    unsigned short* hr = H + (size_t)row * DHID;
    ushort4 raw = ((const ushort4*)hr)[tid];
    float v0 = bf2f(raw.x), v1 = bf2f(raw.y), v2 = bf2f(raw.z), v3 = bf2f(raw.w);
    float s = v0 + v1 + v2 + v3;
    float s2 = v0 * v0 + v1 * v1 + v2 * v2 + v3 * v3;
#pragma unroll
    for (int o = 32; o; o >>= 1) {
        s += __shfl_xor(s, o, 64);
        s2 += __shfl_xor(s2, o, 64);
    }
    __shared__ float red[8];
    const int w = tid >> 6;
    if ((tid & 63) == 0) { red[w] = s; red[4 + w] = s2; }
    __syncthreads();
    s = red[0] + red[1] + red[2] + red[3];
    s2 = red[4] + red[5] + red[6] + red[7];
    const float inv = 1.0f / 1024.0f;
    const float mu = s * inv;
    const float var = fmaxf(s2 * inv - mu * mu, 0.f);
    const float rstd = rsqrtf(var + 1e-5f);
    const float* g = gamma + dom * DHID + tid * 4;
    const float* b = beta + dom * DHID + tid * 4;
    ushort4 o4;
    o4.x = f2bf(fmaxf((v0 - mu) * rstd * g[0] + b[0], 0.f));
    o4.y = f2bf(fmaxf((v1 - mu) * rstd * g[1] + b[1], 0.f));
    o4.z = f2bf(fmaxf((v2 - mu) * rstd * g[2] + b[2], 0.f));
    o4.w = f2bf(fmaxf((v3 - mu) * rstd * g[3] + b[3], 0.f));
    ((ushort4*)hr)[tid] = o4;
}

// ---------------- launch ------------------------------------------------------
extern "C" void kernel_launch(void* const* d_in, const int* in_sizes, int n_in,
                              void* d_out, int out_size, void* d_ws, size_t ws_size,
                              hipStream_t stream) {
    const float* x = (const float*)d_in[0];
    const int* dt = (const int*)d_in[1];
    const float* W1 = (const float*)d_in[2];
    const float* b1 = (const float*)d_in[3];
    const float* gamma = (const float*)d_in[4];
    const float* beta = (const float*)d_in[5];
    const float* W2 = (const float*)d_in[6];
    const float* b2 = (const float*)d_in[7];
    float* out = (float*)d_out;

    char* ws = (char*)d_ws;
    size_t off = 0;
    auto take = [&](size_t nbytes) -> char* {
        char* p = ws + off;
        off = (off + nbytes + 255) & ~(size_t)255;
        return p;
    };
    unsigned short* W1T = (unsigned short*)take((size_t)ND * DHID * DIN * 2);   // [8,1024,256]
    unsigned short* W2T = (unsigned short*)take((size_t)ND * DOUT * DHID * 2);  // [8,256,1024]
    unsigned short* XS  = (unsigned short*)take((size_t)MPAD * DIN * 2);
    unsigned short* H   = (unsigned short*)take((size_t)MPAD * DHID * 2);
    int* PERM   = (int*)take(MPAD * 4);
    int* ROWDOM = (int*)take(MPAD * 4);
    int* CNT    = (int*)take(64);            // counts[8] then cursors[8]
    int2* META  = (int2*)take(NTILES * 8);
    (void)ws_size; (void)n_in; (void)in_sizes; (void)out_size;

    int* COUNTS = CNT;
    int* CURSORS = CNT + 8;

    transpose_bf16<<<dim3(DHID / 32, DIN / 32, ND), 256, 0, stream>>>(W1, W1T, DIN, DHID);
    transpose_bf16<<<dim3(DOUT / 32, DHID / 32, ND), 256, 0, stream>>>(W2, W2T, DHID, DOUT);
    zero_init<<<(MPAD + 255) / 256, 256, 0, stream>>>(PERM, ROWDOM, CNT);
    histo<<<NROWS / 256, 256, 0, stream>>>(dt, COUNTS);
    make_meta<<<1, 1, 0, stream>>>(COUNTS, CURSORS, META);
    gather_rows<<<NROWS / 64, 256, 0, stream>>>(x, dt, CURSORS, PERM, ROWDOM, XS);
    gemm_bt<DIN, false><<<dim3(NTILES, DHID / 128), 256, 0, stream>>>(
        XS, W1T, b1, META, nullptr, H, nullptr, DHID);
    ln_relu<<<MPAD, 256, 0, stream>>>(H, gamma, beta, ROWDOM);
    gemm_bt<DHID, true><<<dim3(NTILES, DOUT / 128), 256, 0, stream>>>(
        H, W2T, b2, META, PERM, nullptr, out, DOUT);
}

// Round 2
// 227.439 us; speedup vs baseline: 1.5693x; 1.5693x over previous
//
#include <hip/hip_runtime.h>
#include <hip/hip_bf16.h>

// DomainEncoder: 8-expert MoE MLP, N=32768, 256 -> 1024 (LN+ReLU) -> 256.
// Pipeline:
//   1. transpose W1,W2 -> bf16 [N,K] ("B^T" layout for the m97 GEMM structure)
//   2. counting-sort rows by domain: histo -> make_meta -> assign_pos (block-
//      aggregated atomics: 8/block, not 1/row) -> copy_rows (coalesced gather)
//   3. GEMM-A: h = x_s @ W1[d]^T + b1   (bf16 MFMA 16x16x32, 128x128 tiles)
//   4. LN + ReLU over h rows (1024 wide), in place, bf16
//   5. GEMM-B: out = g @ W2[d]^T + b2, scattered back through perm (fp32 out)

#define ND 8
#define NROWS 32768
#define DIN 256
#define DHID 1024
#define DOUT 256
#define MPAD 33792          // 32768 + 8*128 worst-case padding
#define NTILES 264          // 256 + 8 worst-case row tiles

typedef short short8 __attribute__((ext_vector_type(8)));
typedef float floatx4 __attribute__((ext_vector_type(4)));

__device__ __forceinline__ unsigned short f2bf(float f) {
    unsigned u = __builtin_bit_cast(unsigned, f);
    unsigned r = u + 0x7fff + ((u >> 16) & 1);   // RNE (inputs finite)
    return (unsigned short)(r >> 16);
}
__device__ __forceinline__ float bf2f(unsigned short h) {
    unsigned u = ((unsigned)h) << 16;
    return __builtin_bit_cast(float, u);
}

#define GLDS16(gp, lp) __builtin_amdgcn_global_load_lds( \
    (const __attribute__((address_space(1))) void*)(gp), \
    (__attribute__((address_space(3))) void*)(lp), 16, 0, 0)

// ---------------- 1. weight transpose fp32[R,C] -> bf16[C,R], per-domain z ----
__global__ void transpose_bf16(const float* __restrict__ in,
                               unsigned short* __restrict__ out,
                               int R, int C) {
    __shared__ float t[32][33];
    const int z = blockIdx.z;
    const int c0 = blockIdx.x * 32, r0 = blockIdx.y * 32;
    const int tx = threadIdx.x & 31, ty = threadIdx.x >> 5;   // 32x8
    const float* src = in + (size_t)z * R * C;
    unsigned short* dst = out + (size_t)z * R * C;
#pragma unroll
    for (int i = 0; i < 32; i += 8)
        t[ty + i][tx] = src[(size_t)(r0 + ty + i) * C + c0 + tx];
    __syncthreads();
#pragma unroll
    for (int i = 0; i < 32; i += 8)
        dst[(size_t)(c0 + ty + i) * R + r0 + tx] = f2bf(t[tx][ty + i]);
}

// ---------------- 2a. init perm/rowdom/counters -------------------------------
__global__ void zero_init(int* __restrict__ perm, int* __restrict__ rowdom,
                          int* __restrict__ cnt) {
    int i = blockIdx.x * 256 + threadIdx.x;
    if (i < MPAD) { perm[i] = -1; rowdom[i] = 0; }
    if (i < 16) cnt[i] = 0;            // counts[8] + cursors[8]
}

// ---------------- 2b. histogram (block-aggregated atomics) --------------------
__global__ void histo(const int* __restrict__ dt, int* __restrict__ counts) {
    __shared__ int lc[ND];
    if (threadIdx.x < ND) lc[threadIdx.x] = 0;
    __syncthreads();
    int i = blockIdx.x * 256 + threadIdx.x;      // grid covers exactly NROWS
    atomicAdd(&lc[dt[i]], 1);
    __syncthreads();
    if (threadIdx.x < ND) atomicAdd(&counts[threadIdx.x], lc[threadIdx.x]);
}

// ---------------- 2c. aligned offsets + tile metadata (single thread) ---------
__global__ void make_meta(const int* __restrict__ counts, int* __restrict__ cursors,
                          int2* __restrict__ meta) {
    if (threadIdx.x == 0 && blockIdx.x == 0) {
        int off = 0, t = 0;
        for (int d = 0; d < ND; d++) {
            cursors[d] = off;
            int nt = (counts[d] + 127) >> 7;
            for (int i = 0; i < nt; i++) meta[t++] = make_int2(d, off + (i << 7));
            off += nt << 7;
        }
        for (; t < NTILES; t++) meta[t] = make_int2(-1, 0);
    }
}

// ---------------- 2d. position assignment: 8 global atomics per 256 rows ------
__global__ __launch_bounds__(256)
void assign_pos(const int* __restrict__ dt, int* __restrict__ cursors,
                int* __restrict__ perm, int* __restrict__ rowdom,
                int* __restrict__ pos) {
    __shared__ int lcnt[ND];
    __shared__ int lbase[ND];
    const int tid = threadIdx.x;
    if (tid < ND) lcnt[tid] = 0;
    __syncthreads();
    const int r = blockIdx.x * 256 + tid;
    const int d = dt[r];
    const int myrank = atomicAdd(&lcnt[d], 1);   // LDS atomic: cheap
    __syncthreads();
    if (tid < ND && lcnt[tid] > 0)
        lbase[tid] = atomicAdd(&cursors[tid], lcnt[tid]);  // 8 global atomics/block
    __syncthreads();
    const int p = lbase[d] + myrank;
    pos[r] = p;
    perm[p] = r;
    rowdom[p] = d;
}

// ---------------- 2e. gather copy: one wave per row, coalesced ---------------
__global__ __launch_bounds__(256)
void copy_rows(const float* __restrict__ x, const int* __restrict__ pos,
               unsigned short* __restrict__ xs) {
    const int tid = threadIdx.x;
    const int lane = tid & 63;
    const int r = blockIdx.x * 4 + (tid >> 6);           // 4 rows per block
    const int p = pos[r];
    float4 v = ((const float4*)(x + (size_t)r * DIN))[lane];   // 16B/lane read
    ushort4 o;
    o.x = f2bf(v.x); o.y = f2bf(v.y); o.z = f2bf(v.z); o.w = f2bf(v.w);
    ((ushort4*)(xs + (size_t)p * DIN))[lane] = o;              // 8B/lane write
}

// ---------------- 3/5. grouped GEMM, m97 structure ---------------------------
// C[128x128] per block, 4 waves in 2x2, each wave 64x64 = 4x4 mfma_16x16x32_bf16.
// A: [MPAD,K] bf16 row-major (sorted rows). Bt: [ND,Ntot,K] bf16 (B^T).
template <int K, bool SCATTER>
__global__ __launch_bounds__(256, 2)
void gemm_bt(const unsigned short* __restrict__ A,
             const unsigned short* __restrict__ Bt,
             const float* __restrict__ bias,
             const int2* __restrict__ meta,
             const int* __restrict__ perm,
             unsigned short* __restrict__ Cbf,
             float* __restrict__ Cf,
             const int Ntot) {
    const int2 md = meta[blockIdx.x];
    const int dom = md.x;
    if (dom < 0) return;
    const int m0 = md.y;
    const int n0 = blockIdx.y * 128;

    __shared__ unsigned short As[128 * 32];   // [m][k], 8 KB
    __shared__ unsigned short Bs[128 * 32];   // [n][k], 8 KB

    const int tid = threadIdx.x;
    const int lane = tid & 63;
    const int w = tid >> 6;            // wave id 0..3
    const int wr = w >> 1, wc = w & 1; // 2x2 wave grid

    const unsigned short* Abase = A + (size_t)m0 * K;
    const unsigned short* Bbase = Bt + (size_t)dom * Ntot * K + (size_t)n0 * K;

    floatx4 acc[4][4];
#pragma unroll
    for (int i = 0; i < 4; i++)
#pragma unroll
        for (int j = 0; j < 4; j++) acc[i][j] = 0.f;

    for (int k0 = 0; k0 < K; k0 += 32) {
        // stage: chunk c = w*128 + it*64 + lane; 16B chunks, LDS dest = base + lane*16
#pragma unroll
        for (int it = 0; it < 2; ++it) {
            const int c = w * 128 + it * 64 + lane;
            const int m = c >> 2, kc = c & 3;
            GLDS16(Abase + (size_t)m * K + k0 + kc * 8, &As[(w * 128 + it * 64) * 8]);
            GLDS16(Bbase + (size_t)m * K + k0 + kc * 8, &Bs[(w * 128 + it * 64) * 8]);
        }
        __syncthreads();   // drains vmcnt before barrier (global_load_lds complete)

        short8 a[4], b[4];
        const int kk = (lane >> 4) * 8;
#pragma unroll
        for (int i = 0; i < 4; i++) {
            const int m = wr * 64 + i * 16 + (lane & 15);
            a[i] = *(const short8*)&As[m * 32 + kk];
            const int n = wc * 64 + i * 16 + (lane & 15);
            b[i] = *(const short8*)&Bs[n * 32 + kk];
        }
#pragma unroll
        for (int i = 0; i < 4; i++)
#pragma unroll
            for (int j = 0; j < 4; j++)
                acc[i][j] = __builtin_amdgcn_mfma_f32_16x16x32_bf16(a[i], b[j], acc[i][j], 0, 0, 0);
        __syncthreads();
    }

    // epilogue: C/D layout col=lane&15, row=(lane>>4)*4+reg  [m89-verified]
    const int quad = lane >> 4;
#pragma unroll
    for (int i = 0; i < 4; i++) {
        const int rowbase = m0 + wr * 64 + i * 16 + quad * 4;
        if (!SCATTER) {
#pragma unroll
            for (int j = 0; j < 4; j++) {
                const int col = n0 + wc * 64 + j * 16 + (lane & 15);
                const float bv = bias[dom * Ntot + col];
#pragma unroll
                for (int r = 0; r < 4; r++)
                    Cbf[(size_t)(rowbase + r) * Ntot + col] = f2bf(acc[i][j][r] + bv);
            }
        } else {
#pragma unroll
            for (int r = 0; r < 4; r++) {
                const int orig = perm[rowbase + r];
                if (orig < 0) continue;     // padding row
#pragma unroll
                for (int j = 0; j < 4; j++) {
                    const int col = n0 + wc * 64 + j * 16 + (lane & 15);
                    Cf[(size_t)orig * Ntot + col] = acc[i][j][r] + bias[dom * Ntot + col];
                }
            }
        }
    }
}

// ---------------- 4. LayerNorm + ReLU over h rows (1024), in place -----------
__global__ __launch_bounds__(256)
void ln_relu(unsigned short* __restrict__ H, const float* __restrict__ gamma,
             const float* __restrict__ beta, const int* __restrict__ rowdom) {
    const int row = blockIdx.x;
    const int tid = threadIdx.x;
    const int dom = rowdom[row];
    unsigned short* hr = H + (size_t)row * DHID;
    ushort4 raw = ((const ushort4*)hr)[tid];
    float v0 = bf2f(raw.x), v1 = bf2f(raw.y), v2 = bf2f(raw.z), v3 = bf2f(raw.w);
    float s = v0 + v1 + v2 + v3;
    float s2 = v0 * v0 + v1 * v1 + v2 * v2 + v3 * v3;
#pragma unroll
    for (int o = 32; o; o >>= 1) {
        s += __shfl_xor(s, o, 64);
        s2 += __shfl_xor(s2, o, 64);
    }
    __shared__ float red[8];
    const int w = tid >> 6;
    if ((tid & 63) == 0) { red[w] = s; red[4 + w] = s2; }
    __syncthreads();
    s = red[0] + red[1] + red[2] + red[3];
    s2 = red[4] + red[5] + red[6] + red[7];
    const float inv = 1.0f / 1024.0f;
    const float mu = s * inv;
    const float var = fmaxf(s2 * inv - mu * mu, 0.f);
    const float rstd = rsqrtf(var + 1e-5f);
    const float* g = gamma + dom * DHID + tid * 4;
    const float* b = beta + dom * DHID + tid * 4;
    ushort4 o4;
    o4.x = f2bf(fmaxf((v0 - mu) * rstd * g[0] + b[0], 0.f));
    o4.y = f2bf(fmaxf((v1 - mu) * rstd * g[1] + b[1], 0.f));
    o4.z = f2bf(fmaxf((v2 - mu) * rstd * g[2] + b[2], 0.f));
    o4.w = f2bf(fmaxf((v3 - mu) * rstd * g[3] + b[3], 0.f));
    ((ushort4*)hr)[tid] = o4;
}

// ---------------- launch ------------------------------------------------------
extern "C" void kernel_launch(void* const* d_in, const int* in_sizes, int n_in,
                              void* d_out, int out_size, void* d_ws, size_t ws_size,
                              hipStream_t stream) {
    const float* x = (const float*)d_in[0];
    const int* dt = (const int*)d_in[1];
    const float* W1 = (const float*)d_in[2];
    const float* b1 = (const float*)d_in[3];
    const float* gamma = (const float*)d_in[4];
    const float* beta = (const float*)d_in[5];
    const float* W2 = (const float*)d_in[6];
    const float* b2 = (const float*)d_in[7];
    float* out = (float*)d_out;

    char* ws = (char*)d_ws;
    size_t off = 0;
    auto take = [&](size_t nbytes) -> char* {
        char* p = ws + off;
        off = (off + nbytes + 255) & ~(size_t)255;
        return p;
    };
    unsigned short* W1T = (unsigned short*)take((size_t)ND * DHID * DIN * 2);   // [8,1024,256]
    unsigned short* W2T = (unsigned short*)take((size_t)ND * DOUT * DHID * 2);  // [8,256,1024]
    unsigned short* XS  = (unsigned short*)take((size_t)MPAD * DIN * 2);
    unsigned short* H   = (unsigned short*)take((size_t)MPAD * DHID * 2);
    int* PERM   = (int*)take(MPAD * 4);
    int* ROWDOM = (int*)take(MPAD * 4);
    int* POS    = (int*)take(NROWS * 4);
    int* CNT    = (int*)take(64);            // counts[8] then cursors[8]
    int2* META  = (int2*)take(NTILES * 8);
    (void)ws_size; (void)n_in; (void)in_sizes; (void)out_size;

    int* COUNTS = CNT;
    int* CURSORS = CNT + 8;

    transpose_bf16<<<dim3(DHID / 32, DIN / 32, ND), 256, 0, stream>>>(W1, W1T, DIN, DHID);
    transpose_bf16<<<dim3(DOUT / 32, DHID / 32, ND), 256, 0, stream>>>(W2, W2T, DHID, DOUT);
    zero_init<<<(MPAD + 255) / 256, 256, 0, stream>>>(PERM, ROWDOM, CNT);
    histo<<<NROWS / 256, 256, 0, stream>>>(dt, COUNTS);
    make_meta<<<1, 1, 0, stream>>>(COUNTS, CURSORS, META);
    assign_pos<<<NROWS / 256, 256, 0, stream>>>(dt, CURSORS, PERM, ROWDOM, POS);
    copy_rows<<<NROWS / 4, 256, 0, stream>>>(x, POS, XS);
    gemm_bt<DIN, false><<<dim3(NTILES, DHID / 128), 256, 0, stream>>>(
        XS, W1T, b1, META, nullptr, H, nullptr, DHID);
    ln_relu<<<MPAD, 256, 0, stream>>>(H, gamma, beta, ROWDOM);
    gemm_bt<DHID, true><<<dim3(NTILES, DOUT / 128), 256, 0, stream>>>(
        H, W2T, b2, META, PERM, nullptr, out, DOUT);
}